// Round 6
// baseline (98.568 us; speedup 1.0000x reference)
//
#include <hip/hip_runtime.h>
#include <hip/hip_bf16.h>

#define NB 16
#define NC 4
#define NL 4096
#define NK 256
#define NS 128
#define NW (NL - NS + 1)           /* 3969 */
#define WPB 256                    /* windows per task */
#define KPB 128                    /* k per block (K split 2-way by blockIdx.x) */
#define XEL 384                    /* staged x elements per channel (255+128=383, +1 pad) */
#define XROW 400                   /* xcp row stride: 800 B = 8-bank offset per row */
#define EPSF 1e-8f

typedef __attribute__((ext_vector_type(8))) short bf16x8;
typedef __attribute__((ext_vector_type(4))) float floatx4;

typedef __attribute__((address_space(3))) unsigned int* lds_ptr_t;
typedef const __attribute__((address_space(1))) unsigned int* gbl_ptr_t;

__device__ inline short f2bf(float f) {
    __hip_bfloat16 h = __float2bfloat16(f);
    short s;
    __builtin_memcpy(&s, &h, sizeof(short));
    return s;
}

__device__ inline void gload_lds16(const void* g, void* l) {
    __builtin_amdgcn_global_load_lds((gbl_ptr_t)g, (lds_ptr_t)l, 16, 0, 0);
}

// K1: normalize shapelets (fp32 in), write bf16 bits PRE-SWIZZLED within each
// 256B row so the main kernel can global_load_lds linearly. One wave per (c,k).
__global__ __launch_bounds__(64)
void norm_shp_kernel(const float* __restrict__ shp, short* __restrict__ shpn) {
    int ck = blockIdx.x;
    int k = ck & (NK - 1);
    int lane = threadIdx.x;
    const float* p = shp + (size_t)ck * NS;
    float v0 = p[lane];
    float v1 = p[lane + 64];
    float ss = v0 * v0 + v1 * v1;
    #pragma unroll
    for (int o = 32; o > 0; o >>= 1) ss += __shfl_xor(ss, o, 64);
    float rn = 1.f / fmaxf(sqrtf(ss), EPSF);
    // swizzled element positions: 16B unit u of row k goes to unit u^(k&15)
    int s0 = lane, s1 = lane + 64;
    int d0 = ((((s0 >> 3) ^ (k & 15)) << 3) | (s0 & 7));
    int d1 = ((((s1 >> 3) ^ (k & 15)) << 3) | (s1 & 7));
    shpn[(size_t)ck * NS + d0] = f2bf(v0 * rn);
    shpn[(size_t)ck * NS + d1] = f2bf(v1 * rn);
}

// K2: merged 512-thread main kernel. Grid = (kq=2, slot=128) = 256 blocks =
// exactly 1/CU, 8 waves. Per block: B (4ch x 128k = 128 KB) staged ONCE via
// gload_lds; 2 tasks of 256 windows. Wave wv: windows (wv>>1)*64..+63,
// k-half (wv&1)*64..+63 -> wave tile 64w x 64k (mt=4, kt=4: A-reads amortized
// 4x over kt). xcp rows padded to 400 shorts -> A b64 reads bank-conflict-free.
__global__ __launch_bounds__(512, 2)
void mcs_main_kernel(const float* __restrict__ x,
                     const short* __restrict__ shpn,
                     float* __restrict__ out) {
    __shared__ bf16x8 bs[NC][KPB * 16];            // 128 KB swizzled B
    __shared__ alignas(16) short xcp[NC][4][XROW]; // 12.5 KB shifted raw-bf16 x
    __shared__ alignas(16) float scratch[NC][XEL]; // 6 KB x^2 -> prefix sums
    __shared__ float invw[NC][WPB];                // 4 KB window inv-norms
    __shared__ float epi[8][64];                   // 2 KB epilogue reduction

    const int kq = blockIdx.x, slot = blockIdx.y;
    const int b = slot >> 3, wslot = slot & 7;
    const int tid = threadIdx.x;
    const int lane = tid & 63, wv = tid >> 6;
    const int m = lane & 15, q = lane >> 4, r = m & 3;
    const int kh = wv & 1, wh = wv >> 1;

    // ---- B staging: ONCE per block, 128 KB, zero VGPR / zero VALU,
    // in flight over the entire task-0 prologue. ----
    {
        const char* gbase = (const char*)shpn + (size_t)(kq * KPB) * NS * 2;
        #pragma unroll
        for (int c = 0; c < NC; c++) {
            const char* gc = gbase + (size_t)c * NK * NS * 2;
            char* lc = (char*)&bs[c][0];
            #pragma unroll
            for (int i = 0; i < 4; i++) {
                int off = (wv * 4 + i) * 1024;
                gload_lds16(gc + off + lane * 16, lc + off);
            }
        }
    }

    // ---- both tasks' x into regs (one burst; thread tid holds element tid) --
    float xv[8];
    #pragma unroll
    for (int t = 0; t < 2; t++) {
        const int g = (wslot * 2 + t) * WPB + tid;
        #pragma unroll
        for (int c = 0; c < NC; c++)
            xv[t * 4 + c] = (tid < XEL && g < NL)
                          ? x[((size_t)b * NC + c) * NL + g] : 0.f;
    }

    float res[2];

    #pragma unroll
    for (int t = 0; t < 2; t++) {
        const int w0 = (wslot * 2 + t) * WPB;

        // ---- stage x: shift-copies (raw bf16) + squares ----
        if (tid < XEL) {
            #pragma unroll
            for (int c = 0; c < NC; c++) {
                float xf = xv[t * 4 + c];
                short hv = f2bf(xf);
                #pragma unroll
                for (int rr = 0; rr < 4; rr++) {
                    int o2 = tid - rr;
                    if (o2 >= 0) xcp[c][rr][o2] = hv;   // xcp[c][r][o] = x[o+r]
                }
                scratch[c][tid] = xf * xf;
            }
        }
        __syncthreads();

        // ---- inclusive prefix scan of x^2: wave c scans channel c (6/lane) --
        if (wv < 4) {
            const int c = wv;
            const int base = lane * 6;
            float v[6];
            #pragma unroll
            for (int i = 0; i < 6; i++) v[i] = scratch[c][base + i];
            #pragma unroll
            for (int i = 1; i < 6; i++) v[i] += v[i - 1];
            float tt = v[5];
            #pragma unroll
            for (int o = 1; o < 64; o <<= 1) {
                float u = __shfl_up(tt, o, 64);
                if (lane >= o) tt += u;
            }
            float excl = tt - v[5];
            #pragma unroll
            for (int i = 0; i < 6; i++) scratch[c][base + i] = v[i] + excl;
        }
        __syncthreads();

        // ---- window inverse norms from prefix sums (2 per thread) ----
        #pragma unroll
        for (int i = 0; i < 2; i++) {
            int ii = tid + 512 * i;
            int c = ii >> 8, o = ii & 255;
            float nn = scratch[c][o + 127] - (o ? scratch[c][o - 1] : 0.f);
            int w = w0 + o;
            invw[c][o] = (w < NW) ? 1.f / fmaxf(sqrtf(fmaxf(nn, 0.f)), EPSF)
                                  : 0.f;
        }
        if (t == 0) asm volatile("s_waitcnt vmcnt(0)" ::: "memory"); // B staged
        __syncthreads();

        // ---- compute: zero global ops, zero barriers ----
        floatx4 tot[4][4];
        #pragma unroll
        for (int mt = 0; mt < 4; mt++)
            #pragma unroll
            for (int kt = 0; kt < 4; kt++)
                tot[mt][kt] = (floatx4){0.f, 0.f, 0.f, 0.f};

        #pragma unroll
        for (int c = 0; c < NC; c++) {
            floatx4 part[4][4];
            #pragma unroll
            for (int s0 = 0; s0 < NS; s0 += 32) {
                bf16x8 a[4];
                #pragma unroll
                for (int mt = 0; mt < 4; mt++) {   // raw bit-copy: zero VALU
                    int ts = wh * 64 + mt * 16 + m + s0 + q * 8;
                    const uint2* pp = (const uint2*)&xcp[c][r][ts - r];
                    union { uint2 uu[2]; bf16x8 v; } cv;
                    cv.uu[0] = pp[0]; cv.uu[1] = pp[1];
                    a[mt] = cv.v;
                }
                int cc = (s0 >> 3) + q;
                #pragma unroll
                for (int kt = 0; kt < 4; kt++) {
                    int k = kh * 64 + kt * 16 + m;   // k&15 == m
                    bf16x8 bf = bs[c][(k << 4) | (cc ^ m)];
                    #pragma unroll
                    for (int mt = 0; mt < 4; mt++) {
                        part[mt][kt] = (s0 == 0)
                            ? __builtin_amdgcn_mfma_f32_16x16x32_bf16(
                                  a[mt], bf, (floatx4){0.f,0.f,0.f,0.f}, 0,0,0)
                            : __builtin_amdgcn_mfma_f32_16x16x32_bf16(
                                  a[mt], bf, part[mt][kt], 0, 0, 0);
                    }
                }
            }
            // fp32 per-channel scale-accumulate: tot += invw[row] * part
            #pragma unroll
            for (int mt = 0; mt < 4; mt++) {
                const float4 iv =
                    *(const float4*)&invw[c][wh * 64 + mt * 16 + q * 4];
                floatx4 ivv = (floatx4){iv.x, iv.y, iv.z, iv.w};
                #pragma unroll
                for (int kt = 0; kt < 4; kt++) tot[mt][kt] += ivv * part[mt][kt];
            }
        }

        // ---- epilogue: wave-max over its 64 windows per k ----
        #pragma unroll
        for (int kt = 0; kt < 4; kt++) {
            floatx4 v0 = tot[0][kt], v1 = tot[1][kt],
                    v2 = tot[2][kt], v3 = tot[3][kt];
            float mx = fmaxf(fmaxf(fmaxf(v0.x, v0.y), fmaxf(v0.z, v0.w)),
                             fmaxf(fmaxf(v1.x, v1.y), fmaxf(v1.z, v1.w)));
            mx = fmaxf(mx, fmaxf(fmaxf(fmaxf(v2.x, v2.y), fmaxf(v2.z, v2.w)),
                                 fmaxf(fmaxf(v3.x, v3.y), fmaxf(v3.z, v3.w))));
            mx = fmaxf(mx, __shfl_xor(mx, 16, 64));
            mx = fmaxf(mx, __shfl_xor(mx, 32, 64));
            if (lane < 16) epi[wv][kt * 16 + lane] = mx;   // own row, no race
        }
        __syncthreads();
        if (tid < 128) {
            // k-local = tid; computed by the 4 wh-waves with kh = tid>>6
            int kh_ = tid >> 6, j = tid & 63;
            float v = fmaxf(fmaxf(epi[kh_][j],     epi[kh_ + 2][j]),
                            fmaxf(epi[kh_ + 4][j], epi[kh_ + 6][j]));
            res[t] = fmaxf(v, 0.f) * 0.25f;   // ReLU + 1/C
        }
        __syncthreads();   // epi/scratch free before next task
    }

    // ---- deferred atomics: fire-and-forget ----
    if (tid < 128) {
        int kg = kq * KPB + tid;
        #pragma unroll
        for (int t = 0; t < 2; t++)
            atomicMax((int*)out + (size_t)b * NK + kg, __float_as_int(res[t]));
    }
}

extern "C" void kernel_launch(void* const* d_in, const int* in_sizes, int n_in,
                              void* d_out, int out_size, void* d_ws, size_t ws_size,
                              hipStream_t stream) {
    (void)in_sizes; (void)n_in; (void)out_size; (void)ws_size;
    const float* x   = (const float*)d_in[0];
    const float* shp = (const float*)d_in[1];
    float* out = (float*)d_out;

    short* shpn = (short*)d_ws;     // 256 KB of workspace

    norm_shp_kernel<<<NC * NK, 64, 0, stream>>>(shp, shpn);
    mcs_main_kernel<<<dim3(2, 128), 512, 0, stream>>>(x, shpn, out);
}

// Round 7
// 71.971 us; speedup vs baseline: 1.3695x; 1.3695x over previous
//
#include <hip/hip_runtime.h>
#include <hip/hip_bf16.h>

#define NB 16
#define NC 4
#define NL 4096
#define NK 256
#define NS 128
#define NW (NL - NS + 1)           /* 3969 */
#define WPB 256                    /* windows per task */
#define KPB 128                    /* k per block (K split 2-way by blockIdx.x) */
#define XEL 384                    /* staged x elements per channel */
#define XROW 400                   /* xcp row stride: 800 B = 8-bank step per row */
#define EPSF 1e-8f

typedef __attribute__((ext_vector_type(8))) _Float16 f16x8;
typedef __attribute__((ext_vector_type(4))) float floatx4;

typedef __attribute__((address_space(3))) unsigned int* lds_ptr_t;
typedef const __attribute__((address_space(1))) unsigned int* gbl_ptr_t;

__device__ inline short f2h(float f) {
    _Float16 h = (_Float16)f;
    short s;
    __builtin_memcpy(&s, &h, sizeof(short));
    return s;
}

__device__ inline void gload_lds16(const void* g, void* l) {
    __builtin_amdgcn_global_load_lds((gbl_ptr_t)g, (lds_ptr_t)l, 16, 0, 0);
}

// K1: normalize shapelets (fp32 in), write fp16 bits PRE-SWIZZLED within each
// 256B row so the main kernel can global_load_lds linearly. One wave per (c,k).
__global__ __launch_bounds__(64)
void norm_shp_kernel(const float* __restrict__ shp, short* __restrict__ shpn) {
    int ck = blockIdx.x;
    int k = ck & (NK - 1);
    int lane = threadIdx.x;
    const float* p = shp + (size_t)ck * NS;
    float v0 = p[lane];
    float v1 = p[lane + 64];
    float ss = v0 * v0 + v1 * v1;
    #pragma unroll
    for (int o = 32; o > 0; o >>= 1) ss += __shfl_xor(ss, o, 64);
    float rn = 1.f / fmaxf(sqrtf(ss), EPSF);
    // swizzled element positions: 16B unit u of row k goes to unit u^(k&15)
    int s0 = lane, s1 = lane + 64;
    int d0 = ((((s0 >> 3) ^ (k & 15)) << 3) | (s0 & 7));
    int d1 = ((((s1 >> 3) ^ (k & 15)) << 3) | (s1 & 7));
    shpn[(size_t)ck * NS + d0] = f2h(v0 * rn);
    shpn[(size_t)ck * NS + d1] = f2h(v1 * rn);
}

// K2: merged 512-thread main kernel, fp16, SINGLE accumulator. Grid =
// (kq=2, slot=128) = 256 blocks = 1/CU, 8 waves. B (4ch x 128k = 128 KB)
// staged ONCE via gload_lds. invw applied to A-fragment rows via packed fp16
// muls BEFORE the MFMA (diag(invw)*A*B == diag(invw)*(A*B)), so one tot[4][4]
// accumulates across channels AND s0 -> no spill. launch_bounds(512,1) lifts
// the 128-VGPR cap that forced round-6's 70 MB scratch spill.
__global__ __launch_bounds__(512, 1)
void mcs_main_kernel(const float* __restrict__ x,
                     const short* __restrict__ shpn,
                     float* __restrict__ out) {
    __shared__ f16x8 bs[NC][KPB * 16];             // 128 KB swizzled B
    __shared__ alignas(16) short xcp[NC][4][XROW]; // 12.5 KB shifted raw-fp16 x
    __shared__ alignas(16) float scratch[NC][XEL]; // 6 KB x^2 -> prefix sums
    __shared__ float invw[NC][WPB];                // 4 KB window inv-norms
    __shared__ float epi[8][64];                   // 2 KB epilogue reduction

    const int kq = blockIdx.x, slot = blockIdx.y;
    const int b = slot >> 3, wslot = slot & 7;
    const int tid = threadIdx.x;
    const int lane = tid & 63, wv = tid >> 6;
    const int m = lane & 15, q = lane >> 4, r = m & 3;
    const int kh = wv & 1, wh = wv >> 1;

    // ---- B staging: ONCE per block, 128 KB, zero VGPR / zero VALU,
    // in flight over the entire task-0 prologue. ----
    {
        const char* gbase = (const char*)shpn + (size_t)(kq * KPB) * NS * 2;
        #pragma unroll
        for (int c = 0; c < NC; c++) {
            const char* gc = gbase + (size_t)c * NK * NS * 2;
            char* lc = (char*)&bs[c][0];
            #pragma unroll
            for (int i = 0; i < 4; i++) {
                int off = (wv * 4 + i) * 1024;
                gload_lds16(gc + off + lane * 16, lc + off);
            }
        }
    }

    // ---- both tasks' x into regs (one burst; thread tid holds element tid) --
    float xv[8];
    #pragma unroll
    for (int t = 0; t < 2; t++) {
        const int g = (wslot * 2 + t) * WPB + tid;
        #pragma unroll
        for (int c = 0; c < NC; c++)
            xv[t * 4 + c] = (tid < XEL && g < NL)
                          ? x[((size_t)b * NC + c) * NL + g] : 0.f;
    }

    float res[2];

    #pragma unroll
    for (int t = 0; t < 2; t++) {
        const int w0 = (wslot * 2 + t) * WPB;

        // ---- stage x: shift-copies (raw fp16) + squares ----
        if (tid < XEL) {
            #pragma unroll
            for (int c = 0; c < NC; c++) {
                float xf = xv[t * 4 + c];
                short hv = f2h(xf);
                #pragma unroll
                for (int rr = 0; rr < 4; rr++) {
                    int o2 = tid - rr;
                    if (o2 >= 0) xcp[c][rr][o2] = hv;   // xcp[c][r][o] = x[o+r]
                }
                scratch[c][tid] = xf * xf;
            }
        }
        __syncthreads();

        // ---- inclusive prefix scan of x^2: wave c scans channel c (6/lane) --
        if (wv < 4) {
            const int c = wv;
            const int base = lane * 6;
            float v[6];
            #pragma unroll
            for (int i = 0; i < 6; i++) v[i] = scratch[c][base + i];
            #pragma unroll
            for (int i = 1; i < 6; i++) v[i] += v[i - 1];
            float tt = v[5];
            #pragma unroll
            for (int o = 1; o < 64; o <<= 1) {
                float u = __shfl_up(tt, o, 64);
                if (lane >= o) tt += u;
            }
            float excl = tt - v[5];
            #pragma unroll
            for (int i = 0; i < 6; i++) scratch[c][base + i] = v[i] + excl;
        }
        __syncthreads();

        // ---- window inverse norms from prefix sums (2 per thread) ----
        #pragma unroll
        for (int i = 0; i < 2; i++) {
            int ii = tid + 512 * i;
            int c = ii >> 8, o = ii & 255;
            float nn = scratch[c][o + 127] - (o ? scratch[c][o - 1] : 0.f);
            int w = w0 + o;
            invw[c][o] = (w < NW) ? 1.f / fmaxf(sqrtf(fmaxf(nn, 0.f)), EPSF)
                                  : 0.f;
        }
        if (t == 0) asm volatile("s_waitcnt vmcnt(0)" ::: "memory"); // B staged
        __syncthreads();

        // ---- compute: single accumulator, zero global ops, zero barriers ----
        floatx4 tot[4][4];
        #pragma unroll
        for (int mt = 0; mt < 4; mt++)
            #pragma unroll
            for (int kt = 0; kt < 4; kt++)
                tot[mt][kt] = (floatx4){0.f, 0.f, 0.f, 0.f};

        #pragma unroll
        for (int c = 0; c < NC; c++) {
            // per-row invw splats for this channel (one row per mt)
            f16x8 ivs[4];
            #pragma unroll
            for (int mt = 0; mt < 4; mt++) {
                _Float16 ih = (_Float16)invw[c][wh * 64 + mt * 16 + m];
                ivs[mt] = (f16x8){ih, ih, ih, ih, ih, ih, ih, ih};
            }
            #pragma unroll
            for (int s0 = 0; s0 < NS; s0 += 32) {
                f16x8 a[4];
                #pragma unroll
                for (int mt = 0; mt < 4; mt++) {   // bit-copy + 4 pk_mul
                    int ts = wh * 64 + mt * 16 + m + s0 + q * 8;
                    const uint2* pp = (const uint2*)&xcp[c][r][ts - r];
                    union { uint2 uu[2]; f16x8 v; } cv;
                    cv.uu[0] = pp[0]; cv.uu[1] = pp[1];
                    a[mt] = cv.v * ivs[mt];        // row-scaled A fragment
                }
                int cc = (s0 >> 3) + q;
                #pragma unroll
                for (int kt = 0; kt < 4; kt++) {
                    int k = kh * 64 + kt * 16 + m;   // k&15 == m
                    f16x8 bf = bs[c][(k << 4) | (cc ^ m)];
                    #pragma unroll
                    for (int mt = 0; mt < 4; mt++)
                        tot[mt][kt] = __builtin_amdgcn_mfma_f32_16x16x32_f16(
                            a[mt], bf, tot[mt][kt], 0, 0, 0);
                }
            }
        }

        // ---- epilogue: wave-max over its 64 windows per k ----
        #pragma unroll
        for (int kt = 0; kt < 4; kt++) {
            floatx4 v0 = tot[0][kt], v1 = tot[1][kt],
                    v2 = tot[2][kt], v3 = tot[3][kt];
            float mx = fmaxf(fmaxf(fmaxf(v0.x, v0.y), fmaxf(v0.z, v0.w)),
                             fmaxf(fmaxf(v1.x, v1.y), fmaxf(v1.z, v1.w)));
            mx = fmaxf(mx, fmaxf(fmaxf(fmaxf(v2.x, v2.y), fmaxf(v2.z, v2.w)),
                                 fmaxf(fmaxf(v3.x, v3.y), fmaxf(v3.z, v3.w))));
            mx = fmaxf(mx, __shfl_xor(mx, 16, 64));
            mx = fmaxf(mx, __shfl_xor(mx, 32, 64));
            if (lane < 16) epi[wv][kt * 16 + lane] = mx;   // own row, no race
        }
        __syncthreads();
        if (tid < 128) {
            // k-local = tid; computed by the 4 wh-waves with kh = tid>>6
            int kh_ = tid >> 6, j = tid & 63;
            float v = fmaxf(fmaxf(epi[kh_][j],     epi[kh_ + 2][j]),
                            fmaxf(epi[kh_ + 4][j], epi[kh_ + 6][j]));
            res[t] = fmaxf(v, 0.f) * 0.25f;   // ReLU + 1/C
        }
        __syncthreads();   // epi/scratch free before next task
    }

    // ---- deferred atomics: fire-and-forget ----
    if (tid < 128) {
        int kg = kq * KPB + tid;
        #pragma unroll
        for (int t = 0; t < 2; t++)
            atomicMax((int*)out + (size_t)b * NK + kg, __float_as_int(res[t]));
    }
}

extern "C" void kernel_launch(void* const* d_in, const int* in_sizes, int n_in,
                              void* d_out, int out_size, void* d_ws, size_t ws_size,
                              hipStream_t stream) {
    (void)in_sizes; (void)n_in; (void)out_size; (void)ws_size;
    const float* x   = (const float*)d_in[0];
    const float* shp = (const float*)d_in[1];
    float* out = (float*)d_out;

    short* shpn = (short*)d_ws;     // 256 KB of workspace

    norm_shp_kernel<<<NC * NK, 64, 0, stream>>>(shp, shpn);
    mcs_main_kernel<<<dim3(2, 128), 512, 0, stream>>>(x, shpn, out);
}

// Round 8
// 69.965 us; speedup vs baseline: 1.4088x; 1.0287x over previous
//
#include <hip/hip_runtime.h>
#include <hip/hip_bf16.h>

#define NB 16
#define NC 4
#define NL 4096
#define NK 256
#define NS 128
#define NW (NL - NS + 1)           /* 3969 */
#define WPB 512                    /* windows per block (one supertask) */
#define KPB 128                    /* k per block (K split 2-way by blockIdx.x) */
#define XEL 640                    /* staged x elements per channel (511+128+1) */
#define XROW 656                   /* xcp row stride: 1312 B = 8-bank step/row */
#define EPSF 1e-8f

typedef __attribute__((ext_vector_type(8))) _Float16 f16x8;
typedef __attribute__((ext_vector_type(2))) _Float16 f16x2;
typedef __attribute__((ext_vector_type(4))) float floatx4;

typedef __attribute__((address_space(3))) unsigned int* lds_ptr_t;
typedef const __attribute__((address_space(1))) unsigned int* gbl_ptr_t;

__device__ inline short f2h(float f) {
    _Float16 h = (_Float16)f;
    short s;
    __builtin_memcpy(&s, &h, sizeof(short));
    return s;
}

__device__ inline void gload_lds16(const void* g, void* l) {
    __builtin_amdgcn_global_load_lds((gbl_ptr_t)g, (lds_ptr_t)l, 16, 0, 0);
}

// K1: normalize shapelets (fp32 in), write fp16 bits PRE-SWIZZLED within each
// 256B row so the main kernel can global_load_lds linearly. One wave per (c,k).
__global__ __launch_bounds__(64)
void norm_shp_kernel(const float* __restrict__ shp, short* __restrict__ shpn) {
    int ck = blockIdx.x;
    int k = ck & (NK - 1);
    int lane = threadIdx.x;
    const float* p = shp + (size_t)ck * NS;
    float v0 = p[lane];
    float v1 = p[lane + 64];
    float ss = v0 * v0 + v1 * v1;
    #pragma unroll
    for (int o = 32; o > 0; o >>= 1) ss += __shfl_xor(ss, o, 64);
    float rn = 1.f / fmaxf(sqrtf(ss), EPSF);
    // swizzled element positions: 16B unit u of row k goes to unit u^(k&15)
    int s0 = lane, s1 = lane + 64;
    int d0 = ((((s0 >> 3) ^ (k & 15)) << 3) | (s0 & 7));
    int d1 = ((((s1 >> 3) ^ (k & 15)) << 3) | (s1 & 7));
    shpn[(size_t)ck * NS + d0] = f2h(v0 * rn);
    shpn[(size_t)ck * NS + d1] = f2h(v1 * rn);
}

// K2: 512-thread SUPERTASK kernel. Grid = (kq=2, slot=128) = 256 blocks =
// 1/CU, 8 waves. One 512-window task per block: single prologue (x stage +
// scan + invw), then one uninterrupted compute burst. Wave wv: windows
// (wv>>1)*128..+127 (mt=8 -> each B LDS read feeds 8 MFMAs), k-half
// (wv&1)*64..+63 (kt=4). tot[8][4] = 128 acc VGPRs, no spill at 8 waves/CU.
// invw/epi alias scratch via register handoff (LDS total 158.5 KB).
__global__ __launch_bounds__(512, 1)
void mcs_main_kernel(const float* __restrict__ x,
                     const short* __restrict__ shpn,
                     float* __restrict__ out) {
    __shared__ f16x8 bs[NC][KPB * 16];             // 128 KB swizzled B
    __shared__ alignas(16) short xcp[NC][4][XROW]; // 20.5 KB shifted fp16 x
    __shared__ union {
        float scratch[NC][XEL];                    // prologue: x^2 -> prefix
        struct { float invw[NC][WPB]; float epi[8][64]; } c;
    } u;                                           // 10.25 KB

    const int kq = blockIdx.x, slot = blockIdx.y;
    const int b = slot >> 3, wslot = slot & 7;
    const int w0 = wslot * WPB;
    const int tid = threadIdx.x;
    const int lane = tid & 63, wv = tid >> 6;
    const int m = lane & 15, q = lane >> 4, r = m & 3;
    const int kh = wv & 1, wh = wv >> 1;

    // ---- B staging: ONCE per block, 128 KB, zero VGPR / zero VALU,
    // in flight over the entire prologue. ----
    {
        const char* gbase = (const char*)shpn + (size_t)(kq * KPB) * NS * 2;
        #pragma unroll
        for (int c = 0; c < NC; c++) {
            const char* gc = gbase + (size_t)c * NK * NS * 2;
            char* lc = (char*)&bs[c][0];
            #pragma unroll
            for (int i = 0; i < 4; i++) {
                int off = (wv * 4 + i) * 1024;
                gload_lds16(gc + off + lane * 16, lc + off);
            }
        }
    }

    // ---- x into regs: thread tid holds elements tid and (tid<128) tid+512 --
    float xv[NC], xv2[NC];
    {
        const int g0 = w0 + tid;
        #pragma unroll
        for (int c = 0; c < NC; c++)
            xv[c] = (g0 < NL) ? x[((size_t)b * NC + c) * NL + g0] : 0.f;
        if (tid < XEL - 512) {
            const int g1 = g0 + 512;
            #pragma unroll
            for (int c = 0; c < NC; c++)
                xv2[c] = (g1 < NL) ? x[((size_t)b * NC + c) * NL + g1] : 0.f;
        }
    }

    // ---- stage x: shift-copies (raw fp16) + squares ----
    #pragma unroll
    for (int c = 0; c < NC; c++) {
        short hv = f2h(xv[c]);
        #pragma unroll
        for (int rr = 0; rr < 4; rr++) {
            int o2 = tid - rr;
            if (o2 >= 0) xcp[c][rr][o2] = hv;       // xcp[c][r][o] = x[o+r]
        }
        u.scratch[c][tid] = xv[c] * xv[c];
        if (tid < XEL - 512) {
            short hv2 = f2h(xv2[c]);
            #pragma unroll
            for (int rr = 0; rr < 4; rr++)
                xcp[c][rr][tid + 512 - rr] = hv2;
            u.scratch[c][tid + 512] = xv2[c] * xv2[c];
        }
    }
    __syncthreads();

    // ---- inclusive prefix scan of x^2: wave c scans channel c (10/lane) ----
    if (wv < 4) {
        const int c = wv;
        const int base = lane * 10;
        float v[10];
        #pragma unroll
        for (int i = 0; i < 10; i++) v[i] = u.scratch[c][base + i];
        #pragma unroll
        for (int i = 1; i < 10; i++) v[i] += v[i - 1];
        float tt = v[9];
        #pragma unroll
        for (int o = 1; o < 64; o <<= 1) {
            float uu = __shfl_up(tt, o, 64);
            if (lane >= o) tt += uu;
        }
        float excl = tt - v[9];
        #pragma unroll
        for (int i = 0; i < 10; i++) u.scratch[c][base + i] = v[i] + excl;
    }
    __syncthreads();

    // ---- window inverse norms: scratch -> regs, barrier, aliased store ----
    float ivreg[4];
    #pragma unroll
    for (int i = 0; i < 4; i++) {
        int ii = tid + 512 * i;
        int c = ii >> 9, o = ii & 511;
        float nn = u.scratch[c][o + 127] - (o ? u.scratch[c][o - 1] : 0.f);
        int w = w0 + o;
        ivreg[i] = (w < NW) ? 1.f / fmaxf(sqrtf(fmaxf(nn, 0.f)), EPSF) : 0.f;
    }
    __syncthreads();   // all scratch reads complete before aliased writes
    #pragma unroll
    for (int i = 0; i < 4; i++) {
        int ii = tid + 512 * i;
        u.c.invw[ii >> 9][ii & 511] = ivreg[i];
    }
    asm volatile("s_waitcnt vmcnt(0)" ::: "memory");   // B staged
    __syncthreads();

    // ---- compute: one uninterrupted burst, zero global ops, zero barriers --
    floatx4 tot[8][4];
    #pragma unroll
    for (int mt = 0; mt < 8; mt++)
        #pragma unroll
        for (int kt = 0; kt < 4; kt++)
            tot[mt][kt] = (floatx4){0.f, 0.f, 0.f, 0.f};

    #pragma unroll
    for (int c = 0; c < NC; c++) {
        // per-row invw half2 splats for this channel (1 VGPR per mt)
        f16x2 iv2[8];
        #pragma unroll
        for (int mt = 0; mt < 8; mt++) {
            _Float16 ih = (_Float16)u.c.invw[c][wh * 128 + mt * 16 + m];
            iv2[mt] = (f16x2){ih, ih};
        }
        #pragma unroll
        for (int s0 = 0; s0 < NS; s0 += 32) {
            f16x8 a[8];
            #pragma unroll
            for (int mt = 0; mt < 8; mt++) {       // b64 pair + 4 pk_mul
                int ts = wh * 128 + mt * 16 + m + s0 + q * 8;
                const uint2* pp = (const uint2*)&xcp[c][r][ts - r];
                union { uint2 uu[2]; f16x8 v; f16x2 h2[4]; } cv;
                cv.uu[0] = pp[0]; cv.uu[1] = pp[1];
                #pragma unroll
                for (int p2 = 0; p2 < 4; p2++) cv.h2[p2] *= iv2[mt];
                a[mt] = cv.v;                       // row-scaled A fragment
            }
            int cc = (s0 >> 3) + q;
            #pragma unroll
            for (int kt = 0; kt < 4; kt++) {
                int k = kh * 64 + kt * 16 + m;     // k&15 == m
                f16x8 bf = bs[c][(k << 4) | (cc ^ m)];
                #pragma unroll
                for (int mt = 0; mt < 8; mt++)     // 8x B-reuse per LDS read
                    tot[mt][kt] = __builtin_amdgcn_mfma_f32_16x16x32_f16(
                        a[mt], bf, tot[mt][kt], 0, 0, 0);
            }
        }
    }

    // ---- epilogue: wave-max over its 128 windows per k ----
    #pragma unroll
    for (int kt = 0; kt < 4; kt++) {
        float mx = -1e30f;
        #pragma unroll
        for (int mt = 0; mt < 8; mt++) {
            floatx4 v = tot[mt][kt];
            mx = fmaxf(mx, fmaxf(fmaxf(v.x, v.y), fmaxf(v.z, v.w)));
        }
        mx = fmaxf(mx, __shfl_xor(mx, 16, 64));
        mx = fmaxf(mx, __shfl_xor(mx, 32, 64));
        if (lane < 16) u.c.epi[wv][kt * 16 + lane] = mx;   // own row, no race
    }
    __syncthreads();
    if (tid < 128) {
        // k-local = tid; computed by the 4 wh-waves with kh = tid>>6
        int kh_ = tid >> 6, j = tid & 63;
        float v = fmaxf(fmaxf(u.c.epi[kh_][j],     u.c.epi[kh_ + 2][j]),
                        fmaxf(u.c.epi[kh_ + 4][j], u.c.epi[kh_ + 6][j]));
        v = fmaxf(v, 0.f) * 0.25f;    // ReLU + 1/C, nonneg -> int-monotonic
        atomicMax((int*)out + (size_t)b * NK + kq * KPB + tid,
                  __float_as_int(v));
    }
}

extern "C" void kernel_launch(void* const* d_in, const int* in_sizes, int n_in,
                              void* d_out, int out_size, void* d_ws, size_t ws_size,
                              hipStream_t stream) {
    (void)in_sizes; (void)n_in; (void)out_size; (void)ws_size;
    const float* x   = (const float*)d_in[0];
    const float* shp = (const float*)d_in[1];
    float* out = (float*)d_out;

    short* shpn = (short*)d_ws;     // 256 KB of workspace

    norm_shp_kernel<<<NC * NK, 64, 0, stream>>>(shp, shpn);
    mcs_main_kernel<<<dim3(2, 128), 512, 0, stream>>>(x, shpn, out);
}